// Round 7
// baseline (273.677 us; speedup 1.0000x reference)
//
#include <hip/hip_runtime.h>

#define S_LEN 256
#define H_DIM 768
#define T_HEADS 13
#define WN 1664
#define NEGV 1.0e12f

typedef __bf16 bf16x8 __attribute__((ext_vector_type(8)));
typedef float f32x4 __attribute__((ext_vector_type(4)));
typedef float f32x16 __attribute__((ext_vector_type(16)));

static __device__ __forceinline__ ushort f2bf(float x) {
  unsigned u = __float_as_uint(x);
  return (ushort)((u + 0x7FFFu + ((u >> 16) & 1u)) >> 16);
}

// ---- prep 1: lhs f32 -> bf16, same [64][256][768] layout ----
__global__ __launch_bounds__(256) void prep_lhs(const float* __restrict__ in,
                                                ushort* __restrict__ outb) {
  size_t base = ((size_t)blockIdx.x * 256 + threadIdx.x) * 8;
  float4 v0 = *reinterpret_cast<const float4*>(in + base);
  float4 v1 = *reinterpret_cast<const float4*>(in + base + 4);
  uint4 u;
  u.x = f2bf(v0.x) | ((unsigned)f2bf(v0.y) << 16);
  u.y = f2bf(v0.z) | ((unsigned)f2bf(v0.w) << 16);
  u.z = f2bf(v1.x) | ((unsigned)f2bf(v1.y) << 16);
  u.w = f2bf(v1.z) | ((unsigned)f2bf(v1.w) << 16);
  *reinterpret_cast<uint4*>(outb + base) = u;
}

// ---- prep 2: W [768][1664] f32 -> Wt [1664][768] bf16 (transpose) ----
__global__ __launch_bounds__(256) void prep_wt(const float* __restrict__ W,
                                               ushort* __restrict__ Wt) {
  __shared__ ushort T[64][68];
  const int blk = blockIdx.x;
  const int k0 = (blk % 12) * 64, c0 = (blk / 12) * 64;
  const int tid = threadIdx.x;
#pragma unroll
  for (int p = 0; p < 4; ++p) {
    int f = p * 256 + tid;
    int r = f >> 4, cg = f & 15;
    float4 v = *reinterpret_cast<const float4*>(W + (size_t)(k0 + r) * WN + c0 + cg * 4);
    T[r][cg * 4 + 0] = f2bf(v.x); T[r][cg * 4 + 1] = f2bf(v.y);
    T[r][cg * 4 + 2] = f2bf(v.z); T[r][cg * 4 + 3] = f2bf(v.w);
  }
  __syncthreads();
  const int orow = tid >> 2, kq = tid & 3;
  ushort tmp[16];
#pragma unroll
  for (int j = 0; j < 16; ++j) tmp[j] = T[kq * 16 + j][orow];
  uint4 u0, u1;
  u0.x = tmp[0] | ((unsigned)tmp[1] << 16);  u0.y = tmp[2] | ((unsigned)tmp[3] << 16);
  u0.z = tmp[4] | ((unsigned)tmp[5] << 16);  u0.w = tmp[6] | ((unsigned)tmp[7] << 16);
  u1.x = tmp[8] | ((unsigned)tmp[9] << 16);  u1.y = tmp[10] | ((unsigned)tmp[11] << 16);
  u1.z = tmp[12] | ((unsigned)tmp[13] << 16); u1.w = tmp[14] | ((unsigned)tmp[15] << 16);
  ushort* dst = Wt + (size_t)(c0 + orow) * H_DIM + k0 + kq * 16;
  *reinterpret_cast<uint4*>(dst) = u0;
  *reinterpret_cast<uint4*>(dst + 8) = u1;
}

// ---- K1: GEMM (BM=128, BN=128=one head, BK=64) + bias + RoPE -> Qb, Kb (bf16) ----
// launch_bounds(256,2): 256-reg cap, NO spills (loop-live ~140 regs).
// XCD mapping: each XCD owns 4 batches at a time -> A(1.5MB)+Wt(2.5MB) fits 4MB L2.
__global__ __launch_bounds__(256, 2) void gemm_rope(
    const ushort* __restrict__ lhsb, const ushort* __restrict__ Wt,
    const float* __restrict__ bias, ushort* __restrict__ Qb,
    ushort* __restrict__ Kb) {
  const int x = blockIdx.x;        // 0..1663
  const int xcd = x & 7;
  const int seq = x >> 3;          // 0..207 (temporal order within XCD)
  const int grp = seq / 104;       // batch-group 0/1
  const int loc = seq % 104;       // 104 = 4 batches * 2 halves * 13 heads
  const int b = (xcd + 8 * grp) * 4 + (loc / 26);
  const int rem = loc % 26;
  const int mrow0 = (rem / 13) * 128;
  const int th = rem % 13;
  const int tid = threadIdx.x;
  const int w = tid >> 6;
  const int lane = tid & 63;
  const int lo = lane & 15;
  const int hi = lane >> 4;

  // staging (36 KB) unioned with epilogue Q/K bounce buffers (32 KB)
  __shared__ union {
    struct { ushort A[128][72]; ushort W[128][72]; } p1;
    struct { ushort Q[128][64]; ushort K[128][64]; } p2;
  } sm;

  const ushort* Ab = lhsb + ((size_t)b * S_LEN + mrow0) * H_DIM;
  const ushort* Wb = Wt + (size_t)th * 128 * H_DIM;

  f32x4 acc[2][8];
#pragma unroll
  for (int mi = 0; mi < 2; ++mi)
#pragma unroll
    for (int ni = 0; ni < 8; ++ni) acc[mi][ni] = (f32x4){0.f, 0.f, 0.f, 0.f};

  uint4 pa[4], pw[4];
#pragma unroll
  for (int p = 0; p < 4; ++p) {
    int f = p * 256 + tid;
    pa[p] = *reinterpret_cast<const uint4*>(Ab + (size_t)(f >> 3) * H_DIM + (f & 7) * 8);
    pw[p] = *reinterpret_cast<const uint4*>(Wb + (size_t)(f >> 3) * H_DIM + (f & 7) * 8);
  }
  for (int k0 = 0; k0 < H_DIM; k0 += 64) {
#pragma unroll
    for (int p = 0; p < 4; ++p) {
      int f = p * 256 + tid;
      *reinterpret_cast<uint4*>(&sm.p1.A[f >> 3][(f & 7) * 8]) = pa[p];
      *reinterpret_cast<uint4*>(&sm.p1.W[f >> 3][(f & 7) * 8]) = pw[p];
    }
    __syncthreads();
    if (k0 + 64 < H_DIM) {
#pragma unroll
      for (int p = 0; p < 4; ++p) {
        int f = p * 256 + tid;
        pa[p] = *reinterpret_cast<const uint4*>(Ab + (size_t)(f >> 3) * H_DIM + k0 + 64 + (f & 7) * 8);
        pw[p] = *reinterpret_cast<const uint4*>(Wb + (size_t)(f >> 3) * H_DIM + k0 + 64 + (f & 7) * 8);
      }
    }
#pragma unroll
    for (int kk = 0; kk < 2; ++kk) {
      bf16x8 af[2];
#pragma unroll
      for (int mi = 0; mi < 2; ++mi)
        af[mi] = *reinterpret_cast<const bf16x8*>(&sm.p1.A[w * 32 + mi * 16 + lo][kk * 32 + hi * 8]);
#pragma unroll
      for (int ni = 0; ni < 8; ++ni) {
        bf16x8 bfr = *reinterpret_cast<const bf16x8*>(&sm.p1.W[ni * 16 + lo][kk * 32 + hi * 8]);
#pragma unroll
        for (int mi = 0; mi < 2; ++mi)
          acc[mi][ni] = __builtin_amdgcn_mfma_f32_16x16x32_bf16(af[mi], bfr, acc[mi][ni], 0, 0, 0);
      }
    }
    __syncthreads();
  }

  // ---- bias + RoPE into LDS bounce buffers ----
  float bj[8];
#pragma unroll
  for (int ni = 0; ni < 8; ++ni) bj[ni] = bias[th * 128 + ni * 16 + lo];

  float inv_[4];
#pragma unroll
  for (int ii = 0; ii < 4; ++ii)
    inv_[ii] = exp2f(-(float)(ii * 8 + (lo >> 1)) * 0.4152410118609203f);  // log2(1e4)/32
  const float sgn = (lo & 1) ? 1.0f : -1.0f;

#pragma unroll
  for (int mi = 0; mi < 2; ++mi) {
#pragma unroll
    for (int r = 0; r < 4; ++r) {
      int ml = w * 32 + mi * 16 + hi * 4 + r;   // local row (16x16 C/D map)
      int m_seq = mrow0 + ml;
#pragma unroll
      for (int ii = 0; ii < 4; ++ii) {
        float sv, cv;
        __sincosf((float)m_seq * inv_[ii], &sv, &cv);
        {
          float v = acc[mi][ii][r] + bj[ii];
          float o = __shfl_xor(v, 1);
          sm.p2.Q[ml][ii * 16 + lo] = f2bf(v * cv + sgn * o * sv);
        }
        {
          float v = acc[mi][ii + 4][r] + bj[ii + 4];
          float o = __shfl_xor(v, 1);
          sm.p2.K[ml][ii * 16 + lo] = f2bf(v * cv + sgn * o * sv);
        }
      }
    }
  }
  __syncthreads();

  // ---- coalesced flush: full 128B lines, cached (L2-resident for K2) ----
  ushort* qbase = Qb + ((size_t)(b * T_HEADS + th) * S_LEN + mrow0) * 64;
  ushort* kbase = Kb + ((size_t)(b * T_HEADS + th) * S_LEN + mrow0) * 64;
#pragma unroll
  for (int p = 0; p < 4; ++p) {
    int f = p * 256 + tid;
    int row = f >> 3, c8 = f & 7;
    *reinterpret_cast<uint4*>(qbase + (size_t)row * 64 + c8 * 8) =
        *reinterpret_cast<const uint4*>(&sm.p2.Q[row][c8 * 8]);
    *reinterpret_cast<uint4*>(kbase + (size_t)row * 64 + c8 * 8) =
        *reinterpret_cast<const uint4*>(&sm.p2.K[row][c8 * 8]);
  }
}

// ---- K2: logits = Q @ K^T per (b,head); no LDS, no barriers; full-line NT stores ----
// XCD mapping matches gemm_rope's batch ownership.
__global__ __launch_bounds__(256, 2) void qk_logits(
    const ushort* __restrict__ Qb, const ushort* __restrict__ Kb,
    const float* __restrict__ amask, float* __restrict__ out) {
  const int x = blockIdx.x;        // 0..831
  const int xcd = x & 7;
  const int seq = x >> 3;          // 0..103
  const int grp = seq / 52;
  const int loc = seq % 52;        // 52 = 4 batches * 13 heads
  const int b = (xcd + 8 * grp) * 4 + loc / 13;
  const int th = loc % 13;
  const int bid = b * T_HEADS + th;
  const int tid = threadIdx.x;
  const int w = tid >> 6;
  const int lane = tid & 63;
  const int l31 = lane & 31;
  const int hi2 = lane >> 5;

  const ushort* qbase = Qb + ((size_t)bid * S_LEN) * 64;
  const ushort* kbase = Kb + ((size_t)bid * S_LEN) * 64;

  // A-frag (32x32x16): row=l31, k=ks*16+hi2*8+j ; B-frag identical mapping.
  bf16x8 qf2[2][4];
#pragma unroll
  for (int mtile = 0; mtile < 2; ++mtile)
#pragma unroll
    for (int ks = 0; ks < 4; ++ks)
      qf2[mtile][ks] = *reinterpret_cast<const bf16x8*>(
          qbase + (size_t)(w * 64 + mtile * 32 + l31) * 64 + ks * 16 + hi2 * 8);

  const size_t outbase = (size_t)bid * (S_LEN * (size_t)S_LEN);
#pragma unroll 1
  for (int nt = 0; nt < 8; ++nt) {
    bf16x8 kf2[4];
#pragma unroll
    for (int ks = 0; ks < 4; ++ks)
      kf2[ks] = *reinterpret_cast<const bf16x8*>(
          kbase + (size_t)(nt * 32 + l31) * 64 + ks * 16 + hi2 * 8);

    const int ncol = nt * 32 + l31;
    const float pad = amask[b * S_LEN + ncol];
    const float sub = (1.0f - pad) * NEGV;

#pragma unroll
    for (int mtile = 0; mtile < 2; ++mtile) {
      f32x16 c2 = {};
#pragma unroll
      for (int ks = 0; ks < 4; ++ks)
        c2 = __builtin_amdgcn_mfma_f32_32x32x16_bf16(qf2[mtile][ks], kf2[ks], c2, 0, 0, 0);

#pragma unroll
      for (int reg = 0; reg < 16; ++reg) {
        int m = w * 64 + mtile * 32 + (reg & 3) + 8 * (reg >> 2) + 4 * hi2;
        float v = c2[reg] * pad - sub;
        if (m > ncol) v -= NEGV;  // tril(.., -1)
        __builtin_nontemporal_store(v * 0.125f, &out[outbase + (size_t)m * S_LEN + ncol]);
      }
    }
  }
}

// ---- fallback fused kernel (R1-structure path, spill-free bounds) ----
template <bool PREP>
__global__ __launch_bounds__(256, 1) void gp_kernel(
    const float* __restrict__ lhs, const float* __restrict__ Wd,
    const float* __restrict__ bias, const float* __restrict__ amask,
    const ushort* __restrict__ lhsb, const ushort* __restrict__ Wt,
    float* __restrict__ out) {
  const int bid0 = blockIdx.x;
  const int bid = (bid0 & 7) * 104 + (bid0 >> 3);
  const int b = bid / T_HEADS;
  const int th = bid % T_HEADS;
  const int wcol0 = th * 128;
  const int tid = threadIdx.x;
  const int w = tid >> 6;
  const int lane = tid & 63;
  const int lo = lane & 15;
  const int hi = lane >> 4;
  const int l31 = lane & 31;
  const int hi2 = lane >> 5;

  __shared__ union {
    struct { ushort A[256][72]; ushort W[128][72]; } p1;
    struct { ushort Q[256][72]; ushort K[256][72]; } p2;
  } sm;
  __shared__ float mask_s[256];

  mask_s[tid] = amask[b * S_LEN + tid];

  f32x4 acc[4][8];
#pragma unroll
  for (int mi = 0; mi < 4; ++mi)
#pragma unroll
    for (int ni = 0; ni < 8; ++ni) acc[mi][ni] = (f32x4){0.f, 0.f, 0.f, 0.f};

  if constexpr (PREP) {
    const ushort* Ab = lhsb + (size_t)b * (S_LEN * H_DIM);
    const ushort* Wb = Wt + (size_t)wcol0 * H_DIM;
    uint4 pa[8], pw[4];
#pragma unroll
    for (int p = 0; p < 8; ++p) {
      int f = p * 256 + tid;
      pa[p] = *reinterpret_cast<const uint4*>(Ab + (size_t)(f >> 3) * H_DIM + (f & 7) * 8);
    }
#pragma unroll
    for (int p = 0; p < 4; ++p) {
      int f = p * 256 + tid;
      pw[p] = *reinterpret_cast<const uint4*>(Wb + (size_t)(f >> 3) * H_DIM + (f & 7) * 8);
    }
    for (int k0 = 0; k0 < H_DIM; k0 += 64) {
#pragma unroll
      for (int p = 0; p < 8; ++p) {
        int f = p * 256 + tid;
        *reinterpret_cast<uint4*>(&sm.p1.A[f >> 3][(f & 7) * 8]) = pa[p];
      }
#pragma unroll
      for (int p = 0; p < 4; ++p) {
        int f = p * 256 + tid;
        *reinterpret_cast<uint4*>(&sm.p1.W[f >> 3][(f & 7) * 8]) = pw[p];
      }
      __syncthreads();
      if (k0 + 64 < H_DIM) {
#pragma unroll
        for (int p = 0; p < 8; ++p) {
          int f = p * 256 + tid;
          pa[p] = *reinterpret_cast<const uint4*>(Ab + (size_t)(f >> 3) * H_DIM + k0 + 64 + (f & 7) * 8);
        }
#pragma unroll
        for (int p = 0; p < 4; ++p) {
          int f = p * 256 + tid;
          pw[p] = *reinterpret_cast<const uint4*>(Wb + (size_t)(f >> 3) * H_DIM + k0 + 64 + (f & 7) * 8);
        }
      }
#pragma unroll
      for (int kk = 0; kk < 2; ++kk) {
        bf16x8 af[4];
#pragma unroll
        for (int mi = 0; mi < 4; ++mi)
          af[mi] = *reinterpret_cast<const bf16x8*>(&sm.p1.A[w * 64 + mi * 16 + lo][kk * 32 + hi * 8]);
#pragma unroll
        for (int ni = 0; ni < 8; ++ni) {
          bf16x8 bfr = *reinterpret_cast<const bf16x8*>(&sm.p1.W[ni * 16 + lo][kk * 32 + hi * 8]);
#pragma unroll
          for (int mi = 0; mi < 4; ++mi)
            acc[mi][ni] = __builtin_amdgcn_mfma_f32_16x16x32_bf16(af[mi], bfr, acc[mi][ni], 0, 0, 0);
        }
      }
      __syncthreads();
    }
  } else {
    const float* Ab = lhs + (size_t)b * (S_LEN * H_DIM);
    const int wc4 = tid & 31, wrg = tid >> 5;
    for (int k0 = 0; k0 < H_DIM; k0 += 64) {
#pragma unroll
      for (int p = 0; p < 16; ++p) {
        int f = p * 256 + tid;
        int m = f >> 4, c4 = f & 15;
        float4 v = *reinterpret_cast<const float4*>(Ab + (size_t)m * H_DIM + k0 + c4 * 4);
        *reinterpret_cast<ushort4*>(&sm.p1.A[m][c4 * 4]) =
            make_ushort4(f2bf(v.x), f2bf(v.y), f2bf(v.z), f2bf(v.w));
      }
      {
        ushort wt[8][4];
#pragma unroll
        for (int r8 = 0; r8 < 8; ++r8) {
          float4 v = *reinterpret_cast<const float4*>(
              Wd + (size_t)(k0 + wrg * 8 + r8) * WN + wcol0 + wc4 * 4);
          wt[r8][0] = f2bf(v.x); wt[r8][1] = f2bf(v.y);
          wt[r8][2] = f2bf(v.z); wt[r8][3] = f2bf(v.w);
        }
#pragma unroll
        for (int cc = 0; cc < 4; ++cc) {
          *reinterpret_cast<ushort4*>(&sm.p1.W[wc4 * 4 + cc][wrg * 8]) =
              make_ushort4(wt[0][cc], wt[1][cc], wt[2][cc], wt[3][cc]);
          *reinterpret_cast<ushort4*>(&sm.p1.W[wc4 * 4 + cc][wrg * 8 + 4]) =
              make_ushort4(wt[4][cc], wt[5][cc], wt[6][cc], wt[7][cc]);
        }
      }
      __syncthreads();
#pragma unroll
      for (int kk = 0; kk < 2; ++kk) {
        bf16x8 af[4];
#pragma unroll
        for (int mi = 0; mi < 4; ++mi)
          af[mi] = *reinterpret_cast<const bf16x8*>(&sm.p1.A[w * 64 + mi * 16 + lo][kk * 32 + hi * 8]);
#pragma unroll
        for (int ni = 0; ni < 8; ++ni) {
          bf16x8 bfr = *reinterpret_cast<const bf16x8*>(&sm.p1.W[ni * 16 + lo][kk * 32 + hi * 8]);
#pragma unroll
          for (int mi = 0; mi < 4; ++mi)
            acc[mi][ni] = __builtin_amdgcn_mfma_f32_16x16x32_bf16(af[mi], bfr, acc[mi][ni], 0, 0, 0);
        }
      }
      __syncthreads();
    }
  }

  float bj[8];
#pragma unroll
  for (int ni = 0; ni < 8; ++ni) bj[ni] = bias[wcol0 + ni * 16 + lo];

  float inv_[4];
#pragma unroll
  for (int ii = 0; ii < 4; ++ii)
    inv_[ii] = exp2f(-(float)(ii * 8 + (lo >> 1)) * 0.4152410118609203f);
  const float sgn = (lo & 1) ? 1.0f : -1.0f;

#pragma unroll
  for (int mi = 0; mi < 4; ++mi) {
#pragma unroll
    for (int r = 0; r < 4; ++r) {
      int m = w * 64 + mi * 16 + hi * 4 + r;
#pragma unroll
      for (int ii = 0; ii < 4; ++ii) {
        float sv, cv;
        __sincosf((float)m * inv_[ii], &sv, &cv);
        {
          float v = acc[mi][ii][r] + bj[ii];
          float o = __shfl_xor(v, 1);
          sm.p2.Q[m][ii * 16 + lo] = f2bf(v * cv + sgn * o * sv);
        }
        {
          float v = acc[mi][ii + 4][r] + bj[ii + 4];
          float o = __shfl_xor(v, 1);
          sm.p2.K[m][ii * 16 + lo] = f2bf(v * cv + sgn * o * sv);
        }
      }
    }
  }
  __syncthreads();

  bf16x8 qf2[2][4];
#pragma unroll
  for (int mtile = 0; mtile < 2; ++mtile)
#pragma unroll
    for (int ks = 0; ks < 4; ++ks)
      qf2[mtile][ks] = *reinterpret_cast<const bf16x8*>(
          &sm.p2.Q[w * 64 + mtile * 32 + l31][ks * 16 + hi2 * 8]);

  const size_t outbase = (size_t)bid * (S_LEN * (size_t)S_LEN);
#pragma unroll 1
  for (int nt = 0; nt < 8; ++nt) {
    bf16x8 kf2[4];
#pragma unroll
    for (int ks = 0; ks < 4; ++ks)
      kf2[ks] = *reinterpret_cast<const bf16x8*>(
          &sm.p2.K[nt * 32 + l31][ks * 16 + hi2 * 8]);

    const int ncol = nt * 32 + l31;
    const float pad = mask_s[ncol];
    const float sub = (1.0f - pad) * NEGV;

#pragma unroll
    for (int mtile = 0; mtile < 2; ++mtile) {
      f32x16 c2 = {};
#pragma unroll
      for (int ks = 0; ks < 4; ++ks)
        c2 = __builtin_amdgcn_mfma_f32_32x32x16_bf16(qf2[mtile][ks], kf2[ks], c2, 0, 0, 0);

#pragma unroll
      for (int reg = 0; reg < 16; ++reg) {
        int m = w * 64 + mtile * 32 + (reg & 3) + 8 * (reg >> 2) + 4 * hi2;
        float v = c2[reg] * pad - sub;
        if (m > ncol) v -= NEGV;
        __builtin_nontemporal_store(v * 0.125f, &out[outbase + (size_t)m * S_LEN + ncol]);
      }
    }
  }
}

extern "C" void kernel_launch(void* const* d_in, const int* in_sizes, int n_in,
                              void* d_out, int out_size, void* d_ws, size_t ws_size,
                              hipStream_t stream) {
  const float* lhs = (const float*)d_in[0];    // (64,256,768) f32
  const float* Wd = (const float*)d_in[1];     // (768,1664) f32
  const float* bias = (const float*)d_in[2];   // (1664,) f32
  const float* amask = (const float*)d_in[3];  // (64,256) f32
  float* out = (float*)d_out;                  // (64,13,256,256) f32

  const size_t lhsb_elems = (size_t)64 * S_LEN * H_DIM;
  const size_t wt_elems = (size_t)WN * H_DIM;
  const size_t qk_elems = (size_t)64 * T_HEADS * S_LEN * 64;
  const size_t need_prep = (lhsb_elems + wt_elems) * sizeof(ushort);
  const size_t need_split = (lhsb_elems + wt_elems + 2 * qk_elems) * sizeof(ushort);

  if (ws_size >= need_split) {
    ushort* lhsb = (ushort*)d_ws;
    ushort* wt = lhsb + lhsb_elems;
    ushort* qb = wt + wt_elems;
    ushort* kb = qb + qk_elems;
    prep_lhs<<<dim3((unsigned)(lhsb_elems / 8 / 256)), 256, 0, stream>>>(lhs, lhsb);
    prep_wt<<<dim3(12 * 26), 256, 0, stream>>>(Wd, wt);
    gemm_rope<<<dim3(128 * T_HEADS), 256, 0, stream>>>(lhsb, wt, bias, qb, kb);
    qk_logits<<<dim3(64 * T_HEADS), 256, 0, stream>>>(qb, kb, amask, out);
  } else if (ws_size >= need_prep) {
    ushort* lhsb = (ushort*)d_ws;
    ushort* wt = lhsb + lhsb_elems;
    prep_lhs<<<dim3((unsigned)(lhsb_elems / 8 / 256)), 256, 0, stream>>>(lhs, lhsb);
    prep_wt<<<dim3(12 * 26), 256, 0, stream>>>(Wd, wt);
    gp_kernel<true><<<dim3(64 * T_HEADS), 256, 0, stream>>>(lhs, Wd, bias, amask, lhsb, wt, out);
  } else {
    gp_kernel<false><<<dim3(64 * T_HEADS), 256, 0, stream>>>(lhs, Wd, bias, amask, nullptr, nullptr, out);
  }
}

// Round 9
// 136.435 us; speedup vs baseline: 2.0059x; 2.0059x over previous
//
#include <hip/hip_runtime.h>

#define S_LEN 256
#define H_DIM 768
#define T_HEADS 13
#define WN 1664
#define NEGV 1.0e12f

typedef __bf16 bf16x8 __attribute__((ext_vector_type(8)));
typedef float f32x4 __attribute__((ext_vector_type(4)));
typedef float f32x16 __attribute__((ext_vector_type(16)));
typedef unsigned int u32x4 __attribute__((ext_vector_type(4)));

static __device__ __forceinline__ ushort f2bf(float x) {
  unsigned u = __float_as_uint(x);
  return (ushort)((u + 0x7FFFu + ((u >> 16) & 1u)) >> 16);
}

// async global->LDS, 16B per lane; LDS dest = wave-uniform base + lane*16
#define GLOAD16(gp, lp)                                                        \
  __builtin_amdgcn_global_load_lds(                                            \
      (const __attribute__((address_space(1))) unsigned int*)(gp),             \
      (__attribute__((address_space(3))) unsigned int*)(lp), 16, 0, 0)

// ---- prep 1: lhs f32 -> bf16, same [64][256][768] layout ----
__global__ __launch_bounds__(256) void prep_lhs(const float* __restrict__ in,
                                                ushort* __restrict__ outb) {
  size_t base = ((size_t)blockIdx.x * 256 + threadIdx.x) * 8;
  float4 v0 = *reinterpret_cast<const float4*>(in + base);
  float4 v1 = *reinterpret_cast<const float4*>(in + base + 4);
  uint4 u;
  u.x = f2bf(v0.x) | ((unsigned)f2bf(v0.y) << 16);
  u.y = f2bf(v0.z) | ((unsigned)f2bf(v0.w) << 16);
  u.z = f2bf(v1.x) | ((unsigned)f2bf(v1.y) << 16);
  u.w = f2bf(v1.z) | ((unsigned)f2bf(v1.w) << 16);
  *reinterpret_cast<uint4*>(outb + base) = u;
}

// ---- prep 2: W [768][1664] f32 -> Wt [1664][768] bf16 (transpose) ----
__global__ __launch_bounds__(256) void prep_wt(const float* __restrict__ W,
                                               ushort* __restrict__ Wt) {
  __shared__ ushort T[64][68];
  const int blk = blockIdx.x;
  const int k0 = (blk % 12) * 64, c0 = (blk / 12) * 64;
  const int tid = threadIdx.x;
#pragma unroll
  for (int p = 0; p < 4; ++p) {
    int f = p * 256 + tid;
    int r = f >> 4, cg = f & 15;
    float4 v = *reinterpret_cast<const float4*>(W + (size_t)(k0 + r) * WN + c0 + cg * 4);
    T[r][cg * 4 + 0] = f2bf(v.x); T[r][cg * 4 + 1] = f2bf(v.y);
    T[r][cg * 4 + 2] = f2bf(v.z); T[r][cg * 4 + 3] = f2bf(v.w);
  }
  __syncthreads();
  const int orow = tid >> 2, kq = tid & 3;
  ushort tmp[16];
#pragma unroll
  for (int j = 0; j < 16; ++j) tmp[j] = T[kq * 16 + j][orow];
  uint4 u0, u1;
  u0.x = tmp[0] | ((unsigned)tmp[1] << 16);  u0.y = tmp[2] | ((unsigned)tmp[3] << 16);
  u0.z = tmp[4] | ((unsigned)tmp[5] << 16);  u0.w = tmp[6] | ((unsigned)tmp[7] << 16);
  u1.x = tmp[8] | ((unsigned)tmp[9] << 16);  u1.y = tmp[10] | ((unsigned)tmp[11] << 16);
  u1.z = tmp[12] | ((unsigned)tmp[13] << 16); u1.w = tmp[14] | ((unsigned)tmp[15] << 16);
  ushort* dst = Wt + (size_t)(c0 + orow) * H_DIM + k0 + kq * 16;
  *reinterpret_cast<uint4*>(dst) = u0;
  *reinterpret_cast<uint4*>(dst + 8) = u1;
}

// ---- K1: GEMM (BM=128, BN=128=one head, BK=64) via global_load_lds (m97 structure)
//      + bias + RoPE, LDS-bounce epilogue, NT full-line stores of Qb/Kb.
// LDS swizzle (rule #21 both-sides involution):
//   staging: LDS slot (row, c16=lane&7) receives global col16 = (lane&7)^(row&7)
//   read:    col16 group (kk*4+hi) read at LDS slot ((kk*4+hi)^(row&7))
__global__ __launch_bounds__(256, 4) void gemm_rope(
    const ushort* __restrict__ lhsb, const ushort* __restrict__ Wt,
    const float* __restrict__ bias, ushort* __restrict__ Qb,
    ushort* __restrict__ Kb) {
  const int x = blockIdx.x;        // 0..1663
  const int xcd = x & 7;
  const int seq = x >> 3;          // 0..207
  const int grp = seq / 104;
  const int loc = seq % 104;       // 4 batches * 2 halves * 13 heads
  const int b = (xcd + 8 * grp) * 4 + (loc / 26);
  const int rem = loc % 26;
  const int mrow0 = (rem / 13) * 128;
  const int th = rem % 13;
  const int tid = threadIdx.x;
  const int w = tid >> 6;
  const int lane = tid & 63;
  const int lo = lane & 15;
  const int hi = lane >> 4;
  const int lrow8 = lane >> 3;                 // 0..7 (row within 8-row stripe)
  const int lc16 = (lane & 7) ^ lrow8;         // pre-swizzled source col16

  __shared__ union {
    struct { ushort A[128 * 64]; ushort W[128 * 64]; } p1;  // 16K + 16K (linear)
    struct { ushort Q[128][72]; ushort K[128][72]; } p2;    // 36K bounce
  } sm;

  const ushort* Ag = lhsb + ((size_t)b * S_LEN + mrow0) * H_DIM;
  const ushort* Wg = Wt + (size_t)th * 128 * H_DIM;

  f32x4 acc[2][8];
#pragma unroll
  for (int mi = 0; mi < 2; ++mi)
#pragma unroll
    for (int ni = 0; ni < 8; ++ni) acc[mi][ni] = (f32x4){0.f, 0.f, 0.f, 0.f};

  for (int k0 = 0; k0 < H_DIM; k0 += 64) {
    // wave w stages rows [w*32, w*32+32) of A and W: 4 gload_lds each
#pragma unroll
    for (int j = 0; j < 4; ++j) {
      const int r0 = w * 32 + j * 8;  // wave-uniform
      GLOAD16(Ag + (size_t)(r0 + lrow8) * H_DIM + k0 + lc16 * 8, &sm.p1.A[r0 * 64]);
      GLOAD16(Wg + (size_t)(r0 + lrow8) * H_DIM + k0 + lc16 * 8, &sm.p1.W[r0 * 64]);
    }
    __syncthreads();  // compiler drains vmcnt before barrier -> tile ready
#pragma unroll
    for (int kk = 0; kk < 2; ++kk) {
      bf16x8 af[2];
#pragma unroll
      for (int mi = 0; mi < 2; ++mi) {
        const int row = w * 32 + mi * 16 + lo;
        af[mi] = *reinterpret_cast<const bf16x8*>(
            &sm.p1.A[row * 64 + (((kk * 4 + hi) ^ (lo & 7)) * 8)]);
      }
#pragma unroll
      for (int ni = 0; ni < 8; ++ni) {
        const int row = ni * 16 + lo;
        bf16x8 bfr = *reinterpret_cast<const bf16x8*>(
            &sm.p1.W[row * 64 + (((kk * 4 + hi) ^ (lo & 7)) * 8)]);
#pragma unroll
        for (int mi = 0; mi < 2; ++mi)
          acc[mi][ni] = __builtin_amdgcn_mfma_f32_16x16x32_bf16(af[mi], bfr, acc[mi][ni], 0, 0, 0);
      }
    }
    __syncthreads();  // protect LDS overwrite next iter
  }

  // ---- bias + RoPE into LDS bounce (union overwrite is post-barrier-safe) ----
  float bj[8];
#pragma unroll
  for (int ni = 0; ni < 8; ++ni) bj[ni] = bias[th * 128 + ni * 16 + lo];

  float inv_[4];
#pragma unroll
  for (int ii = 0; ii < 4; ++ii)
    inv_[ii] = exp2f(-(float)(ii * 8 + (lo >> 1)) * 0.4152410118609203f);  // log2(1e4)/32
  const float sgn = (lo & 1) ? 1.0f : -1.0f;

#pragma unroll
  for (int mi = 0; mi < 2; ++mi) {
#pragma unroll
    for (int r = 0; r < 4; ++r) {
      int ml = w * 32 + mi * 16 + hi * 4 + r;   // local row (16x16 C/D map, verified)
      int m_seq = mrow0 + ml;
#pragma unroll
      for (int ii = 0; ii < 4; ++ii) {
        float sv, cv;
        __sincosf((float)m_seq * inv_[ii], &sv, &cv);
        {
          float v = acc[mi][ii][r] + bj[ii];
          float o = __shfl_xor(v, 1);
          sm.p2.Q[ml][ii * 16 + lo] = f2bf(v * cv + sgn * o * sv);
        }
        {
          float v = acc[mi][ii + 4][r] + bj[ii + 4];
          float o = __shfl_xor(v, 1);
          sm.p2.K[ml][ii * 16 + lo] = f2bf(v * cv + sgn * o * sv);
        }
      }
    }
  }
  __syncthreads();

  // ---- NT full-line flush: bypass L2 so A/Wt stay resident ----
  ushort* qbase = Qb + ((size_t)(b * T_HEADS + th) * S_LEN + mrow0) * 64;
  ushort* kbase = Kb + ((size_t)(b * T_HEADS + th) * S_LEN + mrow0) * 64;
#pragma unroll
  for (int p = 0; p < 4; ++p) {
    int f = p * 256 + tid;
    int row = f >> 3, c8 = f & 7;
    __builtin_nontemporal_store(
        *reinterpret_cast<const u32x4*>(&sm.p2.Q[row][c8 * 8]),
        reinterpret_cast<u32x4*>(qbase + (size_t)row * 64 + c8 * 8));
    __builtin_nontemporal_store(
        *reinterpret_cast<const u32x4*>(&sm.p2.K[row][c8 * 8]),
        reinterpret_cast<u32x4*>(kbase + (size_t)row * 64 + c8 * 8));
  }
}

// ---- K2: logits = Q @ K^T per (b,head); no LDS, no barriers; full-line NT stores ----
__global__ __launch_bounds__(256, 2) void qk_logits(
    const ushort* __restrict__ Qb, const ushort* __restrict__ Kb,
    const float* __restrict__ amask, float* __restrict__ out) {
  const int x = blockIdx.x;        // 0..831
  const int xcd = x & 7;
  const int seq = x >> 3;          // 0..103
  const int grp = seq / 52;
  const int loc = seq % 52;        // 4 batches * 13 heads
  const int b = (xcd + 8 * grp) * 4 + loc / 13;
  const int th = loc % 13;
  const int bid = b * T_HEADS + th;
  const int tid = threadIdx.x;
  const int w = tid >> 6;
  const int lane = tid & 63;
  const int l31 = lane & 31;
  const int hi2 = lane >> 5;

  const ushort* qbase = Qb + ((size_t)bid * S_LEN) * 64;
  const ushort* kbase = Kb + ((size_t)bid * S_LEN) * 64;

  // A-frag (32x32x16): row=l31, k=ks*16+hi2*8+j ; B-frag identical mapping.
  bf16x8 qf2[2][4];
#pragma unroll
  for (int mtile = 0; mtile < 2; ++mtile)
#pragma unroll
    for (int ks = 0; ks < 4; ++ks)
      qf2[mtile][ks] = *reinterpret_cast<const bf16x8*>(
          qbase + (size_t)(w * 64 + mtile * 32 + l31) * 64 + ks * 16 + hi2 * 8);

  const size_t outbase = (size_t)bid * (S_LEN * (size_t)S_LEN);
#pragma unroll 1
  for (int nt = 0; nt < 8; ++nt) {
    bf16x8 kf2[4];
#pragma unroll
    for (int ks = 0; ks < 4; ++ks)
      kf2[ks] = *reinterpret_cast<const bf16x8*>(
          kbase + (size_t)(nt * 32 + l31) * 64 + ks * 16 + hi2 * 8);

    const int ncol = nt * 32 + l31;
    const float pad = amask[b * S_LEN + ncol];
    const float sub = (1.0f - pad) * NEGV;

#pragma unroll
    for (int mtile = 0; mtile < 2; ++mtile) {
      f32x16 c2 = {};
#pragma unroll
      for (int ks = 0; ks < 4; ++ks)
        c2 = __builtin_amdgcn_mfma_f32_32x32x16_bf16(qf2[mtile][ks], kf2[ks], c2, 0, 0, 0);

#pragma unroll
      for (int reg = 0; reg < 16; ++reg) {
        int m = w * 64 + mtile * 32 + (reg & 3) + 8 * (reg >> 2) + 4 * hi2;
        float v = c2[reg] * pad - sub;
        if (m > ncol) v -= NEGV;  // tril(.., -1)
        __builtin_nontemporal_store(v * 0.125f, &out[outbase + (size_t)m * S_LEN + ncol]);
      }
    }
  }
}

// ---- fallback fused kernel (R4-class, known-correct) ----
__global__ __launch_bounds__(256, 1) void gp_fallback(
    const float* __restrict__ lhs, const float* __restrict__ Wd,
    const float* __restrict__ bias, const float* __restrict__ amask,
    float* __restrict__ out) {
  const int bid0 = blockIdx.x;
  const int bid = (bid0 & 7) * 104 + (bid0 >> 3);
  const int b = bid / T_HEADS;
  const int th = bid % T_HEADS;
  const int wcol0 = th * 128;
  const int tid = threadIdx.x;
  const int w = tid >> 6;
  const int lane = tid & 63;
  const int lo = lane & 15;
  const int hi = lane >> 4;
  const int l31 = lane & 31;
  const int hi2 = lane >> 5;

  __shared__ union {
    struct { ushort A[256][72]; ushort W[128][72]; } p1;
    struct { ushort Q[256][72]; ushort K[256][72]; } p2;
  } sm;
  __shared__ float mask_s[256];

  mask_s[tid] = amask[b * S_LEN + tid];

  f32x4 acc[4][8];
#pragma unroll
  for (int mi = 0; mi < 4; ++mi)
#pragma unroll
    for (int ni = 0; ni < 8; ++ni) acc[mi][ni] = (f32x4){0.f, 0.f, 0.f, 0.f};

  const float* Ab = lhs + (size_t)b * (S_LEN * H_DIM);
  const int wc4 = tid & 31, wrg = tid >> 5;
  for (int k0 = 0; k0 < H_DIM; k0 += 64) {
#pragma unroll
    for (int p = 0; p < 16; ++p) {
      int f = p * 256 + tid;
      int m = f >> 4, c4 = f & 15;
      float4 v = *reinterpret_cast<const float4*>(Ab + (size_t)m * H_DIM + k0 + c4 * 4);
      *reinterpret_cast<ushort4*>(&sm.p1.A[m][c4 * 4]) =
          make_ushort4(f2bf(v.x), f2bf(v.y), f2bf(v.z), f2bf(v.w));
    }
    {
      ushort wt[8][4];
#pragma unroll
      for (int r8 = 0; r8 < 8; ++r8) {
        float4 v = *reinterpret_cast<const float4*>(
            Wd + (size_t)(k0 + wrg * 8 + r8) * WN + wcol0 + wc4 * 4);
        wt[r8][0] = f2bf(v.x); wt[r8][1] = f2bf(v.y);
        wt[r8][2] = f2bf(v.z); wt[r8][3] = f2bf(v.w);
      }
#pragma unroll
      for (int cc = 0; cc < 4; ++cc) {
        *reinterpret_cast<ushort4*>(&sm.p1.W[wc4 * 4 + cc][wrg * 8]) =
            make_ushort4(wt[0][cc], wt[1][cc], wt[2][cc], wt[3][cc]);
        *reinterpret_cast<ushort4*>(&sm.p1.W[wc4 * 4 + cc][wrg * 8 + 4]) =
            make_ushort4(wt[4][cc], wt[5][cc], wt[6][cc], wt[7][cc]);
      }
    }
    __syncthreads();
#pragma unroll
    for (int kk = 0; kk < 2; ++kk) {
      bf16x8 af[4];
#pragma unroll
      for (int mi = 0; mi < 4; ++mi)
        af[mi] = *reinterpret_cast<const bf16x8*>(&sm.p1.A[w * 64 + mi * 16 + lo][kk * 32 + hi * 8]);
#pragma unroll
      for (int ni = 0; ni < 8; ++ni) {
        bf16x8 bfr = *reinterpret_cast<const bf16x8*>(&sm.p1.W[ni * 16 + lo][kk * 32 + hi * 8]);
#pragma unroll
        for (int mi = 0; mi < 4; ++mi)
          acc[mi][ni] = __builtin_amdgcn_mfma_f32_16x16x32_bf16(af[mi], bfr, acc[mi][ni], 0, 0, 0);
      }
    }
    __syncthreads();
  }

  float bj[8];
#pragma unroll
  for (int ni = 0; ni < 8; ++ni) bj[ni] = bias[wcol0 + ni * 16 + lo];

  float inv_[4];
#pragma unroll
  for (int ii = 0; ii < 4; ++ii)
    inv_[ii] = exp2f(-(float)(ii * 8 + (lo >> 1)) * 0.4152410118609203f);
  const float sgn = (lo & 1) ? 1.0f : -1.0f;

#pragma unroll
  for (int mi = 0; mi < 4; ++mi) {
#pragma unroll
    for (int r = 0; r < 4; ++r) {
      int m = w * 64 + mi * 16 + hi * 4 + r;
#pragma unroll
      for (int ii = 0; ii < 4; ++ii) {
        float sv, cv;
        __sincosf((float)m * inv_[ii], &sv, &cv);
        {
          float v = acc[mi][ii][r] + bj[ii];
          float o = __shfl_xor(v, 1);
          sm.p2.Q[m][ii * 16 + lo] = f2bf(v * cv + sgn * o * sv);
        }
        {
          float v = acc[mi][ii + 4][r] + bj[ii + 4];
          float o = __shfl_xor(v, 1);
          sm.p2.K[m][ii * 16 + lo] = f2bf(v * cv + sgn * o * sv);
        }
      }
    }
  }
  __syncthreads();

  bf16x8 qf2[2][4];
#pragma unroll
  for (int mtile = 0; mtile < 2; ++mtile)
#pragma unroll
    for (int ks = 0; ks < 4; ++ks)
      qf2[mtile][ks] = *reinterpret_cast<const bf16x8*>(
          &sm.p2.Q[w * 64 + mtile * 32 + l31][ks * 16 + hi2 * 8]);

  const size_t outbase = (size_t)bid * (S_LEN * (size_t)S_LEN);
#pragma unroll 1
  for (int nt = 0; nt < 8; ++nt) {
    bf16x8 kf2[4];
#pragma unroll
    for (int ks = 0; ks < 4; ++ks)
      kf2[ks] = *reinterpret_cast<const bf16x8*>(
          &sm.p2.K[nt * 32 + l31][ks * 16 + hi2 * 8]);

    const int ncol = nt * 32 + l31;
    const float pad = mask_s[ncol];
    const float sub = (1.0f - pad) * NEGV;

#pragma unroll
    for (int mtile = 0; mtile < 2; ++mtile) {
      f32x16 c2 = {};
#pragma unroll
      for (int ks = 0; ks < 4; ++ks)
        c2 = __builtin_amdgcn_mfma_f32_32x32x16_bf16(qf2[mtile][ks], kf2[ks], c2, 0, 0, 0);

#pragma unroll
      for (int reg = 0; reg < 16; ++reg) {
        int m = w * 64 + mtile * 32 + (reg & 3) + 8 * (reg >> 2) + 4 * hi2;
        float v = c2[reg] * pad - sub;
        if (m > ncol) v -= NEGV;
        __builtin_nontemporal_store(v * 0.125f, &out[outbase + (size_t)m * S_LEN + ncol]);
      }
    }
  }
}

extern "C" void kernel_launch(void* const* d_in, const int* in_sizes, int n_in,
                              void* d_out, int out_size, void* d_ws, size_t ws_size,
                              hipStream_t stream) {
  const float* lhs = (const float*)d_in[0];    // (64,256,768) f32
  const float* Wd = (const float*)d_in[1];     // (768,1664) f32
  const float* bias = (const float*)d_in[2];   // (1664,) f32
  const float* amask = (const float*)d_in[3];  // (64,256) f32
  float* out = (float*)d_out;                  // (64,13,256,256) f32

  const size_t lhsb_elems = (size_t)64 * S_LEN * H_DIM;
  const size_t wt_elems = (size_t)WN * H_DIM;
  const size_t qk_elems = (size_t)64 * T_HEADS * S_LEN * 64;
  const size_t need_split = (lhsb_elems + wt_elems + 2 * qk_elems) * sizeof(ushort);

  if (ws_size >= need_split) {
    ushort* lhsb = (ushort*)d_ws;
    ushort* wt = lhsb + lhsb_elems;
    ushort* qb = wt + wt_elems;
    ushort* kb = qb + qk_elems;
    prep_lhs<<<dim3((unsigned)(lhsb_elems / 8 / 256)), 256, 0, stream>>>(lhs, lhsb);
    prep_wt<<<dim3(12 * 26), 256, 0, stream>>>(Wd, wt);
    gemm_rope<<<dim3(128 * T_HEADS), 256, 0, stream>>>(lhsb, wt, bias, qb, kb);
    qk_logits<<<dim3(64 * T_HEADS), 256, 0, stream>>>(qb, kb, amask, out);
  } else {
    gp_fallback<<<dim3(64 * T_HEADS), 256, 0, stream>>>(lhs, Wd, bias, amask, out);
  }
}